// Round 7
// baseline (281.516 us; speedup 1.0000x reference)
//
#include <hip/hip_runtime.h>
#include <math.h>

#define H_DIM 2048
#define NUM_V 32
#define DK 128
#define DV 128
#define KSZ 4
#define KEY_DIM 2048
#define VALUE_DIM 4096
#define CONV_DIM 8192

// workspace layout (floats):
#define WS_QKV   0       // 8192
#define WS_Z     8192    // 4096
#define WS_B     12288   // 32
#define WS_A     12320   // 32
#define WS_XN    12352   // 4096 (normed core, pre-gate)
#define WS_CTR   24576   // 2 x u32 barrier counters (zeroed per call via memsetAsync)

#define NBLK 1024

__device__ __forceinline__ float wave_reduce_sum(float v) {
#pragma unroll
    for (int off = 32; off > 0; off >>= 1) v += __shfl_down(v, off, 64);
    return v;
}

// hand-rolled grid barrier: all NBLK blocks are co-resident (4/CU guaranteed by
// __launch_bounds__(256,4): LDS 22.3KB*4=89KB<160KB, VGPR<=128), so spin is safe.
__device__ __forceinline__ void gbar(unsigned* c, unsigned target) {
    __syncthreads();
    if (threadIdx.x == 0) {
        __hip_atomic_fetch_add(c, 1u, __ATOMIC_ACQ_REL, __HIP_MEMORY_SCOPE_AGENT);
        unsigned spins = 0;
        while (__hip_atomic_load(c, __ATOMIC_ACQUIRE, __HIP_MEMORY_SCOPE_AGENT) < target) {
            __builtin_amdgcn_s_sleep(2);
            if (++spins > 100000000u) break;   // safety valve: never hang the GPU
        }
    }
    __syncthreads();
}

__global__ __launch_bounds__(256, 4) void fused_decode_kernel(
        const float* __restrict__ h,
        const float* __restrict__ conv_state,
        const float* __restrict__ rec_in,
        const float* __restrict__ conv_w,
        const float* __restrict__ qkv_w,
        const float* __restrict__ z_w,
        const float* __restrict__ b_w,
        const float* __restrict__ a_w,
        const float* __restrict__ out_proj_w,
        const float* __restrict__ dt_bias,
        const float* __restrict__ A_log,
        const float* __restrict__ norm_w,
        float* __restrict__ ws,
        float* __restrict__ hidden_out,
        float* __restrict__ new_conv_state,
        float* __restrict__ rec_out) {
    unsigned* ctr = (unsigned*)(ws + WS_CTR);

    const int t = threadIdx.x;
    const int lane = t & 63;
    const int w = t >> 6;                  // wave in block (0..3)
    const int gw = blockIdx.x * 4 + w;     // global wave (0..4095)
    const float4* h4 = (const float4*)h;

    __shared__ float qc[DK], kc[DK], vc[DV], dl[DV];
    __shared__ float part[8][DV];
    __shared__ float red[4];
    __shared__ float4 out_lds[VALUE_DIM / 4];   // 16 KB
    __shared__ float hacc[4];

    // ================= P0: qkv + b + a projections (8256 rows) =================
    for (int row = gw; row < CONV_DIM + 2 * NUM_V; row += 4096) {
        const float* rp;
        float* dst;
        if (row < CONV_DIM) {
            rp = qkv_w + (size_t)row * H_DIM;
            dst = ws + WS_QKV + row;
        } else if (row < CONV_DIM + NUM_V) {
            int r = row - CONV_DIM;
            rp = b_w + (size_t)r * H_DIM;
            dst = ws + WS_B + r;
        } else {
            int r = row - CONV_DIM - NUM_V;
            rp = a_w + (size_t)r * H_DIM;
            dst = ws + WS_A + r;
        }
        const float4* r4 = (const float4*)rp;
        float acc = 0.f;
#pragma unroll
        for (int i = 0; i < 8; ++i) {
            float4 w4 = r4[lane + 64 * i];
            float4 hv = h4[lane + 64 * i];
            acc += w4.x * hv.x + w4.y * hv.y + w4.z * hv.z + w4.w * hv.w;
        }
        acc = wave_reduce_sum(acc);
        if (lane == 0) *dst = acc;
    }

    gbar(&ctr[0], NBLK);

    // ===== P1: blocks 0..31 = head update; blocks 32..1023 = z projection =====
    if (blockIdx.x < 32) {
        const int n = blockIdx.x;
        const int sh = n >> 1;   // shared q/k head (VPK=2)

        // fused causal-conv + silu for this head's q/k/v slices
        for (int idx = t; idx < 384; idx += 256) {
            int slice = idx >> 7;   // 0=q,1=k,2=v
            int j = idx & 127;
            int c;
            if (slice == 0)      c = sh * DK + j;
            else if (slice == 1) c = KEY_DIM + sh * DK + j;
            else                 c = 2 * KEY_DIM + n * DV + j;
            float4 cs = ((const float4*)conv_state)[c];
            float4 cw = ((const float4*)conv_w)[c];
            float mq = ws[WS_QKV + c];
            float pre = cs.y * cw.x + cs.z * cw.y + cs.w * cw.z + mq * cw.w;
            float so = pre / (1.f + expf(-pre));   // silu
            if (slice == 0)      qc[j] = so;
            else if (slice == 1) kc[j] = so;
            else                 vc[j] = so;
            float4 ns; ns.x = cs.y; ns.y = cs.z; ns.z = cs.w; ns.w = mq;
            ((float4*)new_conv_state)[c] = ns;   // q/k double-written identically
        }
        __syncthreads();

        // l2-norms of q and k (wave0 -> q, wave1 -> k)
        if (t < 64) {
            float s = qc[t] * qc[t] + qc[t + 64] * qc[t + 64];
            s = wave_reduce_sum(s);
            if (lane == 0) red[0] = s;
        } else if (t < 128) {
            int j = t - 64;
            float s = kc[j] * kc[j] + kc[j + 64] * kc[j + 64];
            s = wave_reduce_sum(s);
            if (lane == 0) red[1] = s;
        }
        __syncthreads();
        if (t < 128) {
            float qin = rsqrtf(red[0] + 1e-6f) * 0.08838834764831845f; // 1/sqrt(128)
            float kin = rsqrtf(red[1] + 1e-6f);
            qc[t] *= qin;
            kc[t] *= kin;
        }

        // per-head scalars
        float bb = ws[WS_B + n];
        float aa = ws[WS_A + n];
        float beta = 1.f / (1.f + expf(-bb));
        float xx = aa + dt_bias[n];
        float sp = (xx > 20.f) ? xx : log1pf(expf(xx));
        float gexp = expf(-expf(A_log[n]) * sp);
        __syncthreads();

        const float4* rn4 = (const float4*)(rec_in + (size_t)n * DK * DV);
        float4* ro4 = (float4*)(rec_out + (size_t)n * DK * DV);
        const int cgp = t & 31;   // float4 column group
        const int chp = t >> 5;   // k-chunk (0..7), 16 k each

        // pass 1: kv_mem
        {
            float4 kv = {0.f, 0.f, 0.f, 0.f};
#pragma unroll
            for (int j = 0; j < 16; ++j) {
                int k = chp * 16 + j;
                float4 r = rn4[k * 32 + cgp];
                float kk = kc[k];
                kv.x += r.x * kk; kv.y += r.y * kk; kv.z += r.z * kk; kv.w += r.w * kk;
            }
            ((float4*)part[chp])[cgp] = kv;
        }
        __syncthreads();
        if (t < DV) {
            float s = 0.f;
#pragma unroll
            for (int c = 0; c < 8; ++c) s += part[c][t];
            s *= gexp;
            dl[t] = (vc[t] - s) * beta;
        }
        __syncthreads();

        // pass 2: rec' = rec*gexp + k (x) delta ; core = rec'^T q
        {
            float4 d4 = ((const float4*)dl)[cgp];
            float4 core = {0.f, 0.f, 0.f, 0.f};
#pragma unroll
            for (int j = 0; j < 16; ++j) {
                int k = chp * 16 + j;
                float4 r = rn4[k * 32 + cgp];
                float kk = kc[k];
                float qq = qc[k];
                float4 val;
                val.x = r.x * gexp + kk * d4.x;
                val.y = r.y * gexp + kk * d4.y;
                val.z = r.z * gexp + kk * d4.z;
                val.w = r.w * gexp + kk * d4.w;
                ro4[k * 32 + cgp] = val;
                core.x += val.x * qq; core.y += val.y * qq;
                core.z += val.z * qq; core.w += val.w * qq;
            }
            ((float4*)part[chp])[cgp] = core;
        }
        __syncthreads();
        if (t < DV) {
            float c = 0.f;
#pragma unroll
            for (int cc = 0; cc < 8; ++cc) c += part[cc][t];
            float s = wave_reduce_sum(c * c);
            if (lane == 0) red[2 + (t >> 6)] = s;
            vc[t] = c;   // stash core
        }
        __syncthreads();
        if (t < DV) {
            float c = vc[t];
            float var = (red[2] + red[3]) * (1.f / DV);
            ws[WS_XN + n * DV + t] = c * rsqrtf(var + 1e-6f) * norm_w[t];
        }
    } else {
        // z projection: 4096 rows over 992 blocks x 4 waves (stride 3968)
        int zw = (blockIdx.x - 32) * 4 + w;   // 0..3967
        for (int r = zw; r < VALUE_DIM; r += 3968) {
            const float4* r4 = (const float4*)(z_w + (size_t)r * H_DIM);
            float acc = 0.f;
#pragma unroll
            for (int i = 0; i < 8; ++i) {
                float4 w4 = r4[lane + 64 * i];
                float4 hv = h4[lane + 64 * i];
                acc += w4.x * hv.x + w4.y * hv.y + w4.z * hv.z + w4.w * hv.w;
            }
            acc = wave_reduce_sum(acc);
            if (lane == 0) ws[WS_Z + r] = acc;
        }
    }

    gbar(&ctr[1], NBLK);

    // ================= P2: gate (xn * silu(z)) into LDS, then out-proj =================
    {
        const float4* xn4 = (const float4*)(ws + WS_XN);
        const float4* z4 = (const float4*)(ws + WS_Z);
        for (int i = t; i < VALUE_DIM / 4; i += 256) {
            float4 x = xn4[i];
            float4 z = z4[i];
            float4 o;
            o.x = x.x * (z.x / (1.f + expf(-z.x)));
            o.y = x.y * (z.y / (1.f + expf(-z.y)));
            o.z = x.z * (z.z / (1.f + expf(-z.z)));
            o.w = x.w * (z.w / (1.f + expf(-z.w)));
            out_lds[i] = o;
        }
    }
    __syncthreads();

    // out-proj: 1024 blocks x 2 rows; each wave does half a row, pair-combine via LDS
    {
        const int row = blockIdx.x * 2 + (w >> 1);   // 0..2047
        const int half = w & 1;
        const float4* r4 = (const float4*)(out_proj_w + (size_t)row * VALUE_DIM);
        float acc = 0.f;
#pragma unroll
        for (int i = 0; i < 8; ++i) {
            int id = half * 512 + lane + 64 * i;
            float4 w4 = r4[id];
            float4 ov = out_lds[id];
            acc += w4.x * ov.x + w4.y * ov.y + w4.z * ov.z + w4.w * ov.w;
        }
        acc = wave_reduce_sum(acc);
        if (lane == 0) hacc[w] = acc;
        __syncthreads();
        if ((w & 1) == 0 && lane == 0) hidden_out[row] = hacc[w] + hacc[w + 1];
    }
}

extern "C" void kernel_launch(void* const* d_in, const int* in_sizes, int n_in,
                              void* d_out, int out_size, void* d_ws, size_t ws_size,
                              hipStream_t stream) {
    const float* h          = (const float*)d_in[0];   // (1,1,2048)
    const float* conv_state = (const float*)d_in[1];   // (1,8192,4)
    const float* rec_in     = (const float*)d_in[2];   // (1,32,128,128)
    const float* conv_w     = (const float*)d_in[3];   // (8192,4)
    const float* qkv_w      = (const float*)d_in[4];   // (8192,2048)
    const float* z_w        = (const float*)d_in[5];   // (4096,2048)
    const float* b_w        = (const float*)d_in[6];   // (32,2048)
    const float* a_w        = (const float*)d_in[7];   // (32,2048)
    const float* out_proj_w = (const float*)d_in[8];   // (2048,4096)
    const float* dt_bias    = (const float*)d_in[9];   // (32,)
    const float* A_log      = (const float*)d_in[10];  // (32,)
    const float* norm_w     = (const float*)d_in[11];  // (128,)

    float* out = (float*)d_out;
    float* hidden_out = out;                           // 2048
    float* new_conv   = out + H_DIM;                   // 32768
    float* rec_out    = out + H_DIM + CONV_DIM * KSZ;  // 524288
    float* ws = (float*)d_ws;

    // zero the two barrier counters every call (graph-capture-safe memset node)
    hipMemsetAsync(ws + WS_CTR, 0, 2 * sizeof(unsigned), stream);

    fused_decode_kernel<<<NBLK, 256, 0, stream>>>(
        h, conv_state, rec_in, conv_w, qkv_w, z_w, b_w, a_w, out_proj_w,
        dt_bias, A_log, norm_w, ws, hidden_out, new_conv, rec_out);
}

// Round 8
// 213.138 us; speedup vs baseline: 1.3208x; 1.3208x over previous
//
#include <hip/hip_runtime.h>
#include <math.h>

#define H_DIM 2048
#define NUM_V 32
#define DK 128
#define DV 128
#define KSZ 4
#define KEY_DIM 2048
#define VALUE_DIM 4096
#define CONV_DIM 8192

// workspace layout (floats):
#define WS_QKV   0       // 8192
#define WS_Z     8192    // 4096
#define WS_B     12288   // 32
#define WS_A     12320   // 32
#define WS_OUT   12352   // 4096 gated output
#define WS_CTR   16448   // 64 lines x 32 u32 (P0 barrier) + 1 line ctr2

#define NBLK 1024
#define NLINES 64
#define LSTRIDE 32          // u32 stride between counter lines (128 B)
#define P0_PER_LINE 16u     // 1024 blocks / 64 lines

__device__ __forceinline__ float wave_reduce_sum(float v) {
#pragma unroll
    for (int off = 32; off > 0; off >>= 1) v += __shfl_down(v, off, 64);
    return v;
}

__global__ __launch_bounds__(256, 4) void fused_decode_kernel(
        const float* __restrict__ h,
        const float* __restrict__ conv_state,
        const float* __restrict__ rec_in,
        const float* __restrict__ conv_w,
        const float* __restrict__ qkv_w,
        const float* __restrict__ z_w,
        const float* __restrict__ b_w,
        const float* __restrict__ a_w,
        const float* __restrict__ out_proj_w,
        const float* __restrict__ dt_bias,
        const float* __restrict__ A_log,
        const float* __restrict__ norm_w,
        float* __restrict__ ws,
        float* __restrict__ hidden_out,
        float* __restrict__ new_conv_state,
        float* __restrict__ rec_out) {
    unsigned* ctr0 = (unsigned*)(ws + WS_CTR);        // 64 spread lines
    unsigned* ctr2 = ctr0 + NLINES * LSTRIDE;         // heads-done counter

    const int t = threadIdx.x;
    const int lane = t & 63;
    const int w = t >> 6;                  // wave in block (0..3)
    const int gw = blockIdx.x * 4 + w;     // global wave (0..4095)
    const float4* h4 = (const float4*)h;

    __shared__ float qc[DK], kc[DK], vc[DV], dl[DV];
    __shared__ float part[8][DV];
    __shared__ float red[4];
    __shared__ float hacc[4];

    // ================= P0: qkv + z + b + a projections (12352 rows) =================
    for (int row = gw; row < CONV_DIM + VALUE_DIM + 2 * NUM_V; row += 4096) {
        const float* rp;
        float* dst;
        if (row < CONV_DIM) {
            rp = qkv_w + (size_t)row * H_DIM;
            dst = ws + WS_QKV + row;
        } else if (row < CONV_DIM + VALUE_DIM) {
            int r = row - CONV_DIM;
            rp = z_w + (size_t)r * H_DIM;
            dst = ws + WS_Z + r;
        } else if (row < CONV_DIM + VALUE_DIM + NUM_V) {
            int r = row - CONV_DIM - VALUE_DIM;
            rp = b_w + (size_t)r * H_DIM;
            dst = ws + WS_B + r;
        } else {
            int r = row - CONV_DIM - VALUE_DIM - NUM_V;
            rp = a_w + (size_t)r * H_DIM;
            dst = ws + WS_A + r;
        }
        const float4* r4 = (const float4*)rp;
        float acc = 0.f;
#pragma unroll
        for (int i = 0; i < 8; ++i) {
            float4 w4 = r4[lane + 64 * i];
            float4 hv = h4[lane + 64 * i];
            acc += w4.x * hv.x + w4.y * hv.y + w4.z * hv.z + w4.w * hv.w;
        }
        acc = wave_reduce_sum(acc);
        if (lane == 0) *dst = acc;
    }
    __syncthreads();   // all 4 waves' P0 stores drained before the release-add
    if (t == 0) {
        __hip_atomic_fetch_add(ctr0 + (blockIdx.x & (NLINES - 1)) * LSTRIDE, 1u,
                               __ATOMIC_RELEASE, __HIP_MEMORY_SCOPE_AGENT);
    }

    // ===== heads (blocks 0..31): wait for P0, then conv + delta-rule + norm + gate =====
    if (blockIdx.x < 32) {
        // P0 barrier wait: wave 0, lane i polls line i (acquire pairs with all releases)
        if (w == 0) {
            unsigned* line = ctr0 + lane * LSTRIDE;
            unsigned spins = 0;
            while (__hip_atomic_load(line, __ATOMIC_ACQUIRE,
                                     __HIP_MEMORY_SCOPE_AGENT) < P0_PER_LINE) {
                __builtin_amdgcn_s_sleep(8);
                if (++spins > 67108864u) break;   // safety valve
            }
        }
        __syncthreads();

        const int n = blockIdx.x;
        const int sh = n >> 1;   // shared q/k head (VPK=2)

        // fused causal-conv + silu for this head's q/k/v slices
        for (int idx = t; idx < 384; idx += 256) {
            int slice = idx >> 7;   // 0=q,1=k,2=v
            int j = idx & 127;
            int c;
            if (slice == 0)      c = sh * DK + j;
            else if (slice == 1) c = KEY_DIM + sh * DK + j;
            else                 c = 2 * KEY_DIM + n * DV + j;
            float4 cs = ((const float4*)conv_state)[c];
            float4 cw = ((const float4*)conv_w)[c];
            float mq = ws[WS_QKV + c];
            float pre = cs.y * cw.x + cs.z * cw.y + cs.w * cw.z + mq * cw.w;
            float so = pre / (1.f + expf(-pre));   // silu
            if (slice == 0)      qc[j] = so;
            else if (slice == 1) kc[j] = so;
            else                 vc[j] = so;
            float4 ns; ns.x = cs.y; ns.y = cs.z; ns.z = cs.w; ns.w = mq;
            ((float4*)new_conv_state)[c] = ns;   // q/k double-written identically
        }
        __syncthreads();

        // l2-norms of q and k (wave0 -> q, wave1 -> k)
        if (t < 64) {
            float s = qc[t] * qc[t] + qc[t + 64] * qc[t + 64];
            s = wave_reduce_sum(s);
            if (lane == 0) red[0] = s;
        } else if (t < 128) {
            int j = t - 64;
            float s = kc[j] * kc[j] + kc[j + 64] * kc[j + 64];
            s = wave_reduce_sum(s);
            if (lane == 0) red[1] = s;
        }
        __syncthreads();
        if (t < 128) {
            float qin = rsqrtf(red[0] + 1e-6f) * 0.08838834764831845f; // 1/sqrt(128)
            float kin = rsqrtf(red[1] + 1e-6f);
            qc[t] *= qin;
            kc[t] *= kin;
        }

        // per-head scalars
        float bb = ws[WS_B + n];
        float aa = ws[WS_A + n];
        float beta = 1.f / (1.f + expf(-bb));
        float xx = aa + dt_bias[n];
        float sp = (xx > 20.f) ? xx : log1pf(expf(xx));
        float gexp = expf(-expf(A_log[n]) * sp);
        __syncthreads();

        const float4* rn4 = (const float4*)(rec_in + (size_t)n * DK * DV);
        float4* ro4 = (float4*)(rec_out + (size_t)n * DK * DV);
        const int cgp = t & 31;   // float4 column group
        const int chp = t >> 5;   // k-chunk (0..7), 16 k each

        // pass 1: kv_mem
        {
            float4 kv = {0.f, 0.f, 0.f, 0.f};
#pragma unroll
            for (int j = 0; j < 16; ++j) {
                int k = chp * 16 + j;
                float4 r = rn4[k * 32 + cgp];
                float kk = kc[k];
                kv.x += r.x * kk; kv.y += r.y * kk; kv.z += r.z * kk; kv.w += r.w * kk;
            }
            ((float4*)part[chp])[cgp] = kv;
        }
        __syncthreads();
        if (t < DV) {
            float s = 0.f;
#pragma unroll
            for (int c = 0; c < 8; ++c) s += part[c][t];
            s *= gexp;
            dl[t] = (vc[t] - s) * beta;
        }
        __syncthreads();

        // pass 2: rec' = rec*gexp + k (x) delta ; core = rec'^T q
        {
            float4 d4 = ((const float4*)dl)[cgp];
            float4 core = {0.f, 0.f, 0.f, 0.f};
#pragma unroll
            for (int j = 0; j < 16; ++j) {
                int k = chp * 16 + j;
                float4 r = rn4[k * 32 + cgp];
                float kk = kc[k];
                float qq = qc[k];
                float4 val;
                val.x = r.x * gexp + kk * d4.x;
                val.y = r.y * gexp + kk * d4.y;
                val.z = r.z * gexp + kk * d4.z;
                val.w = r.w * gexp + kk * d4.w;
                ro4[k * 32 + cgp] = val;
                core.x += val.x * qq; core.y += val.y * qq;
                core.z += val.z * qq; core.w += val.w * qq;
            }
            ((float4*)part[chp])[cgp] = core;
        }
        __syncthreads();
        if (t < DV) {
            float c = 0.f;
#pragma unroll
            for (int cc = 0; cc < 8; ++cc) c += part[cc][t];
            float s = wave_reduce_sum(c * c);
            if (lane == 0) red[2 + (t >> 6)] = s;
            vc[t] = c;   // stash core
        }
        __syncthreads();
        if (t < DV) {
            float c = vc[t];
            float var = (red[2] + red[3]) * (1.f / DV);
            float xn = c * rsqrtf(var + 1e-6f) * norm_w[t];
            float zv = ws[WS_Z + n * DV + t];
            float silz = zv / (1.f + expf(-zv));
            ws[WS_OUT + n * DV + t] = xn * silz;   // gated output
        }
        __syncthreads();   // gated stores drained before release-add
        if (t == 0) {
            __hip_atomic_fetch_add(ctr2, 1u, __ATOMIC_ACQ_REL, __HIP_MEMORY_SCOPE_AGENT);
        }
    }

    // ===== out-proj: every block does 2 rows (1024 x 2 = 2048) =====
    // preload W into registers BEFORE waiting -> W stream overlaps head compute
    {
        const int row = blockIdx.x * 2 + (w >> 1);   // 0..2047
        const int half = w & 1;
        const float4* r4 = (const float4*)(out_proj_w + (size_t)row * VALUE_DIM);
        float4 wreg[8];
#pragma unroll
        for (int i = 0; i < 8; ++i) wreg[i] = r4[half * 512 + lane + 64 * i];

        if (t == 0) {
            unsigned spins = 0;
            while (__hip_atomic_load(ctr2, __ATOMIC_ACQUIRE,
                                     __HIP_MEMORY_SCOPE_AGENT) < 32u) {
                __builtin_amdgcn_s_sleep(8);
                if (++spins > 67108864u) break;   // safety valve
            }
        }
        __syncthreads();

        const float4* o4 = (const float4*)(ws + WS_OUT);
        float acc = 0.f;
#pragma unroll
        for (int i = 0; i < 8; ++i) {
            float4 ov = o4[half * 512 + lane + 64 * i];
            acc += wreg[i].x * ov.x + wreg[i].y * ov.y +
                   wreg[i].z * ov.z + wreg[i].w * ov.w;
        }
        acc = wave_reduce_sum(acc);
        if (lane == 0) hacc[w] = acc;
        __syncthreads();
        if ((w & 1) == 0 && lane == 0) hidden_out[row] = hacc[w] + hacc[w + 1];
    }
}

extern "C" void kernel_launch(void* const* d_in, const int* in_sizes, int n_in,
                              void* d_out, int out_size, void* d_ws, size_t ws_size,
                              hipStream_t stream) {
    const float* h          = (const float*)d_in[0];   // (1,1,2048)
    const float* conv_state = (const float*)d_in[1];   // (1,8192,4)
    const float* rec_in     = (const float*)d_in[2];   // (1,32,128,128)
    const float* conv_w     = (const float*)d_in[3];   // (8192,4)
    const float* qkv_w      = (const float*)d_in[4];   // (8192,2048)
    const float* z_w        = (const float*)d_in[5];   // (4096,2048)
    const float* b_w        = (const float*)d_in[6];   // (32,2048)
    const float* a_w        = (const float*)d_in[7];   // (32,2048)
    const float* out_proj_w = (const float*)d_in[8];   // (2048,4096)
    const float* dt_bias    = (const float*)d_in[9];   // (32,)
    const float* A_log      = (const float*)d_in[10];  // (32,)
    const float* norm_w     = (const float*)d_in[11];  // (128,)

    float* out = (float*)d_out;
    float* hidden_out = out;                           // 2048
    float* new_conv   = out + H_DIM;                   // 32768
    float* rec_out    = out + H_DIM + CONV_DIM * KSZ;  // 524288
    float* ws = (float*)d_ws;

    // zero the barrier counters every call (graph-capture-safe memset node)
    hipMemsetAsync(ws + WS_CTR, 0, (NLINES * LSTRIDE + LSTRIDE) * sizeof(unsigned),
                   stream);

    fused_decode_kernel<<<NBLK, 256, 0, stream>>>(
        h, conv_state, rec_in, conv_w, qkv_w, z_w, b_w, a_w, out_proj_w,
        dt_bias, A_log, norm_w, ws, hidden_out, new_conv, rec_out);
}

// Round 10
// 76.733 us; speedup vs baseline: 3.6688x; 2.7777x over previous
//
#include <hip/hip_runtime.h>
#include <math.h>

#define H_DIM 2048
#define NUM_V 32
#define DK 128
#define DV 128
#define KSZ 4
#define KEY_DIM 2048
#define VALUE_DIM 4096
#define CONV_DIM 8192

// workspace layout (floats):
#define WS_QKV   0       // 8192
#define WS_Z     8192    // 4096
#define WS_B     12288   // 32
#define WS_A     12320   // 32
#define WS_OUT   12352   // 4096 gated output
#define WS_CTR   16448   // ctr0: 64 lines x 32 u32 ; ctr2: 32 lines x 32 u32

#define NBLK 1024
#define NLINES 64
#define LSTRIDE 32          // u32 stride between counter lines (128 B)
#define P0_PER_LINE 16u     // 1024 blocks / 64 lines

__device__ __forceinline__ float wave_reduce_sum(float v) {
#pragma unroll
    for (int off = 32; off > 0; off >>= 1) v += __shfl_down(v, off, 64);
    return v;
}

__global__ __launch_bounds__(256, 4) void fused_decode_kernel(
        const float* __restrict__ h,
        const float* __restrict__ conv_state,
        const float* __restrict__ rec_in,
        const float* __restrict__ conv_w,
        const float* __restrict__ qkv_w,
        const float* __restrict__ z_w,
        const float* __restrict__ b_w,
        const float* __restrict__ a_w,
        const float* __restrict__ out_proj_w,
        const float* __restrict__ dt_bias,
        const float* __restrict__ A_log,
        const float* __restrict__ norm_w,
        float* __restrict__ ws,
        float* __restrict__ hidden_out,
        float* __restrict__ new_conv_state,
        float* __restrict__ rec_out) {
    unsigned* ctr0 = (unsigned*)(ws + WS_CTR);        // 64 spread lines (P0 barrier)
    unsigned* ctr2 = ctr0 + NLINES * LSTRIDE;         // 32 spread lines (heads done)

    const int t = threadIdx.x;
    const int lane = t & 63;
    const int w = t >> 6;                  // wave in block (0..3)
    const int gw = blockIdx.x * 4 + w;     // global wave (0..4095)
    const float4* h4 = (const float4*)h;

    __shared__ float qc[DK], kc[DK], vc[DV], dl[DV];
    __shared__ float part[8][DV];
    __shared__ float red[4];
    __shared__ float hacc[4];

    // ================= P0: qkv + z + b + a projections (12352 rows) =================
    for (int row = gw; row < CONV_DIM + VALUE_DIM + 2 * NUM_V; row += 4096) {
        const float* rp;
        float* dst;
        if (row < CONV_DIM) {
            rp = qkv_w + (size_t)row * H_DIM;
            dst = ws + WS_QKV + row;
        } else if (row < CONV_DIM + VALUE_DIM) {
            int r = row - CONV_DIM;
            rp = z_w + (size_t)r * H_DIM;
            dst = ws + WS_Z + r;
        } else if (row < CONV_DIM + VALUE_DIM + NUM_V) {
            int r = row - CONV_DIM - VALUE_DIM;
            rp = b_w + (size_t)r * H_DIM;
            dst = ws + WS_B + r;
        } else {
            int r = row - CONV_DIM - VALUE_DIM - NUM_V;
            rp = a_w + (size_t)r * H_DIM;
            dst = ws + WS_A + r;
        }
        const float4* r4 = (const float4*)rp;
        float acc = 0.f;
#pragma unroll
        for (int i = 0; i < 8; ++i) {
            float4 w4 = r4[lane + 64 * i];
            float4 hv = h4[lane + 64 * i];
            acc += w4.x * hv.x + w4.y * hv.y + w4.z * hv.z + w4.w * hv.w;
        }
        acc = wave_reduce_sum(acc);
        if (lane == 0) *dst = acc;
    }
    __syncthreads();   // all 4 waves' P0 stores issued before the release-add
    if (t == 0) {
        // RELEASE: vmcnt drain + L2 writeback makes our plain ws stores LLC-visible
        __hip_atomic_fetch_add(ctr0 + (blockIdx.x & (NLINES - 1)) * LSTRIDE, 1u,
                               __ATOMIC_RELEASE, __HIP_MEMORY_SCOPE_AGENT);
    }

    // ===== heads (blocks 0..31): wait for P0, then conv + delta-rule + norm + gate =====
    if (blockIdx.x < 32) {
        // P0 wait: wave 0, lane i polls line i with RELAXED loads (no cache ops)
        if (w == 0) {
            unsigned* line = ctr0 + lane * LSTRIDE;
            unsigned spins = 0;
            while (true) {
                unsigned v = __hip_atomic_load(line, __ATOMIC_RELAXED,
                                               __HIP_MEMORY_SCOPE_AGENT);
                if (__all(v >= P0_PER_LINE)) break;
                __builtin_amdgcn_s_sleep(4);
                if (++spins > 67108864u) break;   // safety valve
            }
        }
        __syncthreads();
        if (t == 0) {
            // ONE acquire per block: invalidate stale caches so plain reads see LLC
            __builtin_amdgcn_fence(__ATOMIC_ACQUIRE, "agent");
        }
        __syncthreads();

        const int n = blockIdx.x;
        const int sh = n >> 1;   // shared q/k head (VPK=2)

        // fused causal-conv + silu for this head's q/k/v slices
        for (int idx = t; idx < 384; idx += 256) {
            int slice = idx >> 7;   // 0=q,1=k,2=v
            int j = idx & 127;
            int c;
            if (slice == 0)      c = sh * DK + j;
            else if (slice == 1) c = KEY_DIM + sh * DK + j;
            else                 c = 2 * KEY_DIM + n * DV + j;
            float4 cs = ((const float4*)conv_state)[c];
            float4 cw = ((const float4*)conv_w)[c];
            float mq = ws[WS_QKV + c];
            float pre = cs.y * cw.x + cs.z * cw.y + cs.w * cw.z + mq * cw.w;
            float so = pre / (1.f + expf(-pre));   // silu
            if (slice == 0)      qc[j] = so;
            else if (slice == 1) kc[j] = so;
            else                 vc[j] = so;
            float4 ns; ns.x = cs.y; ns.y = cs.z; ns.z = cs.w; ns.w = mq;
            ((float4*)new_conv_state)[c] = ns;   // q/k double-written identically
        }
        __syncthreads();

        // l2-norms of q and k (wave0 -> q, wave1 -> k)
        if (t < 64) {
            float s = qc[t] * qc[t] + qc[t + 64] * qc[t + 64];
            s = wave_reduce_sum(s);
            if (lane == 0) red[0] = s;
        } else if (t < 128) {
            int j = t - 64;
            float s = kc[j] * kc[j] + kc[j + 64] * kc[j + 64];
            s = wave_reduce_sum(s);
            if (lane == 0) red[1] = s;
        }
        __syncthreads();
        if (t < 128) {
            float qin = rsqrtf(red[0] + 1e-6f) * 0.08838834764831845f; // 1/sqrt(128)
            float kin = rsqrtf(red[1] + 1e-6f);
            qc[t] *= qin;
            kc[t] *= kin;
        }

        // per-head scalars
        float bb = ws[WS_B + n];
        float aa = ws[WS_A + n];
        float beta = 1.f / (1.f + expf(-bb));
        float xx = aa + dt_bias[n];
        float sp = (xx > 20.f) ? xx : log1pf(expf(xx));
        float gexp = expf(-expf(A_log[n]) * sp);
        __syncthreads();

        const float4* rn4 = (const float4*)(rec_in + (size_t)n * DK * DV);
        float4* ro4 = (float4*)(rec_out + (size_t)n * DK * DV);
        const int cgp = t & 31;   // float4 column group
        const int chp = t >> 5;   // k-chunk (0..7), 16 k each

        // pass 1: kv_mem
        {
            float4 kv = {0.f, 0.f, 0.f, 0.f};
#pragma unroll
            for (int j = 0; j < 16; ++j) {
                int k = chp * 16 + j;
                float4 r = rn4[k * 32 + cgp];
                float kk = kc[k];
                kv.x += r.x * kk; kv.y += r.y * kk; kv.z += r.z * kk; kv.w += r.w * kk;
            }
            ((float4*)part[chp])[cgp] = kv;
        }
        __syncthreads();
        if (t < DV) {
            float s = 0.f;
#pragma unroll
            for (int c = 0; c < 8; ++c) s += part[c][t];
            s *= gexp;
            dl[t] = (vc[t] - s) * beta;
        }
        __syncthreads();

        // pass 2: rec' = rec*gexp + k (x) delta ; core = rec'^T q
        {
            float4 d4 = ((const float4*)dl)[cgp];
            float4 core = {0.f, 0.f, 0.f, 0.f};
#pragma unroll
            for (int j = 0; j < 16; ++j) {
                int k = chp * 16 + j;
                float4 r = rn4[k * 32 + cgp];
                float kk = kc[k];
                float qq = qc[k];
                float4 val;
                val.x = r.x * gexp + kk * d4.x;
                val.y = r.y * gexp + kk * d4.y;
                val.z = r.z * gexp + kk * d4.z;
                val.w = r.w * gexp + kk * d4.w;
                ro4[k * 32 + cgp] = val;
                core.x += val.x * qq; core.y += val.y * qq;
                core.z += val.z * qq; core.w += val.w * qq;
            }
            ((float4*)part[chp])[cgp] = core;
        }
        __syncthreads();
        if (t < DV) {
            float c = 0.f;
#pragma unroll
            for (int cc = 0; cc < 8; ++cc) c += part[cc][t];
            float s = wave_reduce_sum(c * c);
            if (lane == 0) red[2 + (t >> 6)] = s;
            vc[t] = c;   // stash core
        }
        __syncthreads();
        if (t < DV) {
            float c = vc[t];
            float var = (red[2] + red[3]) * (1.f / DV);
            float xn = c * rsqrtf(var + 1e-6f) * norm_w[t];
            float zv = ws[WS_Z + n * DV + t];
            float silz = zv / (1.f + expf(-zv));
            ws[WS_OUT + n * DV + t] = xn * silz;   // gated output
        }
        __syncthreads();   // gated stores issued before release-add
        if (t == 0) {
            __hip_atomic_fetch_add(ctr2 + blockIdx.x * LSTRIDE, 1u,
                                   __ATOMIC_RELEASE, __HIP_MEMORY_SCOPE_AGENT);
        }
    }

    // ===== out-proj: every block does 2 rows (1024 x 2 = 2048) =====
    // preload W into registers BEFORE waiting -> W stream overlaps head compute
    {
        const int row = blockIdx.x * 2 + (w >> 1);   // 0..2047
        const int half = w & 1;
        const float4* r4 = (const float4*)(out_proj_w + (size_t)row * VALUE_DIM);
        float4 wreg[8];
#pragma unroll
        for (int i = 0; i < 8; ++i) wreg[i] = r4[half * 512 + lane + 64 * i];

        // heads-done wait: wave 0, lanes 0..31 poll one line each, RELAXED
        if (w == 0) {
            unsigned* line = ctr2 + (lane & 31) * LSTRIDE;
            unsigned spins = 0;
            while (true) {
                unsigned v = (lane < 32)
                    ? __hip_atomic_load(line, __ATOMIC_RELAXED, __HIP_MEMORY_SCOPE_AGENT)
                    : 1u;
                if (__all(v >= 1u)) break;
                __builtin_amdgcn_s_sleep(4);
                if (++spins > 67108864u) break;   // safety valve
            }
        }
        __syncthreads();
        if (t == 0) {
            __builtin_amdgcn_fence(__ATOMIC_ACQUIRE, "agent");
        }
        __syncthreads();

        const float4* o4 = (const float4*)(ws + WS_OUT);
        float acc = 0.f;
#pragma unroll
        for (int i = 0; i < 8; ++i) {
            float4 ov = o4[half * 512 + lane + 64 * i];
            acc += wreg[i].x * ov.x + wreg[i].y * ov.y +
                   wreg[i].z * ov.z + wreg[i].w * ov.w;
        }
        acc = wave_reduce_sum(acc);
        if (lane == 0) hacc[w] = acc;
        __syncthreads();
        if ((w & 1) == 0 && lane == 0) hidden_out[row] = hacc[w] + hacc[w + 1];
    }
}

extern "C" void kernel_launch(void* const* d_in, const int* in_sizes, int n_in,
                              void* d_out, int out_size, void* d_ws, size_t ws_size,
                              hipStream_t stream) {
    const float* h          = (const float*)d_in[0];   // (1,1,2048)
    const float* conv_state = (const float*)d_in[1];   // (1,8192,4)
    const float* rec_in     = (const float*)d_in[2];   // (1,32,128,128)
    const float* conv_w     = (const float*)d_in[3];   // (8192,4)
    const float* qkv_w      = (const float*)d_in[4];   // (8192,2048)
    const float* z_w        = (const float*)d_in[5];   // (4096,2048)
    const float* b_w        = (const float*)d_in[6];   // (32,2048)
    const float* a_w        = (const float*)d_in[7];   // (32,2048)
    const float* out_proj_w = (const float*)d_in[8];   // (2048,4096)
    const float* dt_bias    = (const float*)d_in[9];   // (32,)
    const float* A_log      = (const float*)d_in[10];  // (32,)
    const float* norm_w     = (const float*)d_in[11];  // (128,)

    float* out = (float*)d_out;
    float* hidden_out = out;                           // 2048
    float* new_conv   = out + H_DIM;                   // 32768
    float* rec_out    = out + H_DIM + CONV_DIM * KSZ;  // 524288
    float* ws = (float*)d_ws;

    // zero all barrier counter lines every call (graph-capture-safe memset node)
    (void)hipMemsetAsync(ws + WS_CTR, 0,
                         (NLINES + 32) * LSTRIDE * sizeof(unsigned), stream);

    fused_decode_kernel<<<NBLK, 256, 0, stream>>>(
        h, conv_state, rec_in, conv_w, qkv_w, z_w, b_w, a_w, out_proj_w,
        dt_bias, A_log, norm_w, ws, hidden_out, new_conv, rec_out);
}

// Round 11
// 46.628 us; speedup vs baseline: 6.0375x; 1.6456x over previous
//
#include <hip/hip_runtime.h>
#include <math.h>

#define H_DIM 2048
#define NUM_V 32
#define DK 128
#define DV 128
#define KSZ 4
#define KEY_DIM 2048
#define VALUE_DIM 4096
#define CONV_DIM 8192

// workspace layout (floats):
#define WS_QKV   0       // 8192
#define WS_Z     8192    // 4096
#define WS_B     12288   // 32
#define WS_A     12320   // 32
#define WS_OUT   12352   // 4096 gated output
#define WS_CTR   16448   // ctr0: 64 lines x 32 u32 ; ctr2: 32 lines x 32 u32

#define NBLK 1024
#define NLINES 64
#define LSTRIDE 32          // u32 stride between counter lines (128 B)
#define P0_PER_LINE 16u     // 1024 blocks / 64 lines

#define AST(p, v) __hip_atomic_store((p), (v), __ATOMIC_RELAXED, __HIP_MEMORY_SCOPE_AGENT)
#define ALD(p)    __hip_atomic_load((p), __ATOMIC_RELAXED, __HIP_MEMORY_SCOPE_AGENT)

__device__ __forceinline__ float wave_reduce_sum(float v) {
#pragma unroll
    for (int off = 32; off > 0; off >>= 1) v += __shfl_down(v, off, 64);
    return v;
}

__global__ __launch_bounds__(256, 4) void fused_decode_kernel(
        const float* __restrict__ h,
        const float* __restrict__ conv_state,
        const float* __restrict__ rec_in,
        const float* __restrict__ conv_w,
        const float* __restrict__ qkv_w,
        const float* __restrict__ z_w,
        const float* __restrict__ b_w,
        const float* __restrict__ a_w,
        const float* __restrict__ out_proj_w,
        const float* __restrict__ dt_bias,
        const float* __restrict__ A_log,
        const float* __restrict__ norm_w,
        float* __restrict__ ws,
        float* __restrict__ hidden_out,
        float* __restrict__ new_conv_state,
        float* __restrict__ rec_out) {
    unsigned* ctr0 = (unsigned*)(ws + WS_CTR);        // 64 spread lines (P0 barrier)
    unsigned* ctr2 = ctr0 + NLINES * LSTRIDE;         // 32 spread lines (heads done)

    const int t = threadIdx.x;
    const int lane = t & 63;
    const int w = t >> 6;                  // wave in block (0..3)
    const int gw = blockIdx.x * 4 + w;     // global wave (0..4095)
    const float4* h4 = (const float4*)h;

    __shared__ float qc[DK], kc[DK], vc[DV], dl[DV];
    __shared__ float part[8][DV];
    __shared__ float red[4];
    __shared__ float hacc[4];

    // ================= P0: qkv + z + b + a projections (12352 rows) =================
    // results stored with sc1 (agent-scope relaxed atomics) -> land in LLC, never
    // dirty in a non-coherent L2 -> NO wbl2 needed to publish them.
    for (int row = gw; row < CONV_DIM + VALUE_DIM + 2 * NUM_V; row += 4096) {
        const float* rp;
        float* dst;
        if (row < CONV_DIM) {
            rp = qkv_w + (size_t)row * H_DIM;
            dst = ws + WS_QKV + row;
        } else if (row < CONV_DIM + VALUE_DIM) {
            int r = row - CONV_DIM;
            rp = z_w + (size_t)r * H_DIM;
            dst = ws + WS_Z + r;
        } else if (row < CONV_DIM + VALUE_DIM + NUM_V) {
            int r = row - CONV_DIM - VALUE_DIM;
            rp = b_w + (size_t)r * H_DIM;
            dst = ws + WS_B + r;
        } else {
            int r = row - CONV_DIM - VALUE_DIM - NUM_V;
            rp = a_w + (size_t)r * H_DIM;
            dst = ws + WS_A + r;
        }
        const float4* r4 = (const float4*)rp;
        float acc = 0.f;
#pragma unroll
        for (int i = 0; i < 8; ++i) {
            float4 w4 = r4[lane + 64 * i];
            float4 hv = h4[lane + 64 * i];
            acc += w4.x * hv.x + w4.y * hv.y + w4.z * hv.z + w4.w * hv.w;
        }
        acc = wave_reduce_sum(acc);
        if (lane == 0) AST(dst, acc);
    }
    // __syncthreads drains every wave's vmcnt (sc1 stores complete at LLC) before
    // the t==0 signal add -> happens-before without any cache-maintenance op.
    __syncthreads();
    if (t == 0) {
        __hip_atomic_fetch_add(ctr0 + (blockIdx.x & (NLINES - 1)) * LSTRIDE, 1u,
                               __ATOMIC_RELAXED, __HIP_MEMORY_SCOPE_AGENT);
    }

    // ===== heads (blocks 0..31): wait for P0, then conv + delta-rule + norm + gate =====
    if (blockIdx.x < 32) {
        // P0 wait: wave 0, lane i polls line i (relaxed sc1 loads, no cache ops)
        if (w == 0) {
            unsigned* line = ctr0 + lane * LSTRIDE;
            unsigned spins = 0;
            while (true) {
                unsigned v = ALD(line);
                if (__all(v >= P0_PER_LINE)) break;
                __builtin_amdgcn_s_sleep(4);
                if (++spins > 67108864u) break;   // safety valve
            }
        }
        __syncthreads();

        const int n = blockIdx.x;
        const int sh = n >> 1;   // shared q/k head (VPK=2)

        // fused causal-conv + silu for this head's q/k/v slices
        for (int idx = t; idx < 384; idx += 256) {
            int slice = idx >> 7;   // 0=q,1=k,2=v
            int j = idx & 127;
            int c;
            if (slice == 0)      c = sh * DK + j;
            else if (slice == 1) c = KEY_DIM + sh * DK + j;
            else                 c = 2 * KEY_DIM + n * DV + j;
            float4 cs = ((const float4*)conv_state)[c];
            float4 cw = ((const float4*)conv_w)[c];
            float mq = ALD(&ws[WS_QKV + c]);   // sc1: read LLC, skip stale L1/L2
            float pre = cs.y * cw.x + cs.z * cw.y + cs.w * cw.z + mq * cw.w;
            float so = pre / (1.f + expf(-pre));   // silu
            if (slice == 0)      qc[j] = so;
            else if (slice == 1) kc[j] = so;
            else                 vc[j] = so;
            float4 ns; ns.x = cs.y; ns.y = cs.z; ns.z = cs.w; ns.w = mq;
            ((float4*)new_conv_state)[c] = ns;   // q/k double-written identically
        }
        __syncthreads();

        // l2-norms of q and k (wave0 -> q, wave1 -> k)
        if (t < 64) {
            float s = qc[t] * qc[t] + qc[t + 64] * qc[t + 64];
            s = wave_reduce_sum(s);
            if (lane == 0) red[0] = s;
        } else if (t < 128) {
            int j = t - 64;
            float s = kc[j] * kc[j] + kc[j + 64] * kc[j + 64];
            s = wave_reduce_sum(s);
            if (lane == 0) red[1] = s;
        }
        __syncthreads();
        if (t < 128) {
            float qin = rsqrtf(red[0] + 1e-6f) * 0.08838834764831845f; // 1/sqrt(128)
            float kin = rsqrtf(red[1] + 1e-6f);
            qc[t] *= qin;
            kc[t] *= kin;
        }

        // per-head scalars
        float bb = ALD(&ws[WS_B + n]);
        float aa = ALD(&ws[WS_A + n]);
        float beta = 1.f / (1.f + expf(-bb));
        float xx = aa + dt_bias[n];
        float sp = (xx > 20.f) ? xx : log1pf(expf(xx));
        float gexp = expf(-expf(A_log[n]) * sp);
        __syncthreads();

        const float4* rn4 = (const float4*)(rec_in + (size_t)n * DK * DV);
        float4* ro4 = (float4*)(rec_out + (size_t)n * DK * DV);
        const int cgp = t & 31;   // float4 column group
        const int chp = t >> 5;   // k-chunk (0..7), 16 k each

        // pass 1: kv_mem
        {
            float4 kv = {0.f, 0.f, 0.f, 0.f};
#pragma unroll
            for (int j = 0; j < 16; ++j) {
                int k = chp * 16 + j;
                float4 r = rn4[k * 32 + cgp];
                float kk = kc[k];
                kv.x += r.x * kk; kv.y += r.y * kk; kv.z += r.z * kk; kv.w += r.w * kk;
            }
            ((float4*)part[chp])[cgp] = kv;
        }
        __syncthreads();
        if (t < DV) {
            float s = 0.f;
#pragma unroll
            for (int c = 0; c < 8; ++c) s += part[c][t];
            s *= gexp;
            dl[t] = (vc[t] - s) * beta;
        }
        __syncthreads();

        // pass 2: rec' = rec*gexp + k (x) delta ; core = rec'^T q
        {
            float4 d4 = ((const float4*)dl)[cgp];
            float4 core = {0.f, 0.f, 0.f, 0.f};
#pragma unroll
            for (int j = 0; j < 16; ++j) {
                int k = chp * 16 + j;
                float4 r = rn4[k * 32 + cgp];
                float kk = kc[k];
                float qq = qc[k];
                float4 val;
                val.x = r.x * gexp + kk * d4.x;
                val.y = r.y * gexp + kk * d4.y;
                val.z = r.z * gexp + kk * d4.z;
                val.w = r.w * gexp + kk * d4.w;
                ro4[k * 32 + cgp] = val;
                core.x += val.x * qq; core.y += val.y * qq;
                core.z += val.z * qq; core.w += val.w * qq;
            }
            ((float4*)part[chp])[cgp] = core;
        }
        __syncthreads();
        if (t < DV) {
            float c = 0.f;
#pragma unroll
            for (int cc = 0; cc < 8; ++cc) c += part[cc][t];
            float s = wave_reduce_sum(c * c);
            if (lane == 0) red[2 + (t >> 6)] = s;
            vc[t] = c;   // stash core
        }
        __syncthreads();
        if (t < DV) {
            float c = vc[t];
            float var = (red[2] + red[3]) * (1.f / DV);
            float xn = c * rsqrtf(var + 1e-6f) * norm_w[t];
            float zv = ALD(&ws[WS_Z + n * DV + t]);
            float silz = zv / (1.f + expf(-zv));
            AST(&ws[WS_OUT + n * DV + t], xn * silz);   // gated output -> LLC
        }
        __syncthreads();   // drains waves 0/1 vmcnt -> WS_OUT at LLC before signal
        if (t == 0) {
            __hip_atomic_fetch_add(ctr2 + blockIdx.x * LSTRIDE, 1u,
                                   __ATOMIC_RELAXED, __HIP_MEMORY_SCOPE_AGENT);
        }
    }

    // ===== out-proj: every block does 2 rows (1024 x 2 = 2048) =====
    // preload W into registers BEFORE waiting -> W stream overlaps head compute
    {
        const int row = blockIdx.x * 2 + (w >> 1);   // 0..2047
        const int half = w & 1;
        const float4* r4 = (const float4*)(out_proj_w + (size_t)row * VALUE_DIM);
        float4 wreg[8];
#pragma unroll
        for (int i = 0; i < 8; ++i) wreg[i] = r4[half * 512 + lane + 64 * i];

        // heads-done wait: wave 0, lanes 0..31 poll one line each, relaxed
        if (w == 0) {
            unsigned* line = ctr2 + (lane & 31) * LSTRIDE;
            unsigned spins = 0;
            while (true) {
                unsigned v = (lane < 32) ? ALD(line) : 1u;
                if (__all(v >= 1u)) break;
                __builtin_amdgcn_s_sleep(4);
                if (++spins > 67108864u) break;   // safety valve
            }
        }
        __syncthreads();

        // gated vector read with sc1 scalar loads (LLC-coherent; stale-L2-proof)
        float* o = ws + WS_OUT;
        float acc = 0.f;
#pragma unroll
        for (int i = 0; i < 8; ++i) {
            int id = (half * 512 + lane + 64 * i) * 4;
            float o0 = ALD(o + id + 0);
            float o1 = ALD(o + id + 1);
            float o2 = ALD(o + id + 2);
            float o3 = ALD(o + id + 3);
            acc += wreg[i].x * o0 + wreg[i].y * o1 + wreg[i].z * o2 + wreg[i].w * o3;
        }
        acc = wave_reduce_sum(acc);
        if (lane == 0) hacc[w] = acc;
        __syncthreads();
        if ((w & 1) == 0 && lane == 0) hidden_out[row] = hacc[w] + hacc[w + 1];
    }
}

extern "C" void kernel_launch(void* const* d_in, const int* in_sizes, int n_in,
                              void* d_out, int out_size, void* d_ws, size_t ws_size,
                              hipStream_t stream) {
    const float* h          = (const float*)d_in[0];   // (1,1,2048)
    const float* conv_state = (const float*)d_in[1];   // (1,8192,4)
    const float* rec_in     = (const float*)d_in[2];   // (1,32,128,128)
    const float* conv_w     = (const float*)d_in[3];   // (8192,4)
    const float* qkv_w      = (const float*)d_in[4];   // (8192,2048)
    const float* z_w        = (const float*)d_in[5];   // (4096,2048)
    const float* b_w        = (const float*)d_in[6];   // (32,2048)
    const float* a_w        = (const float*)d_in[7];   // (32,2048)
    const float* out_proj_w = (const float*)d_in[8];   // (2048,4096)
    const float* dt_bias    = (const float*)d_in[9];   // (32,)
    const float* A_log      = (const float*)d_in[10];  // (32,)
    const float* norm_w     = (const float*)d_in[11];  // (128,)

    float* out = (float*)d_out;
    float* hidden_out = out;                           // 2048
    float* new_conv   = out + H_DIM;                   // 32768
    float* rec_out    = out + H_DIM + CONV_DIM * KSZ;  // 524288
    float* ws = (float*)d_ws;

    // zero all barrier counter lines every call (graph-capture-safe memset node)
    (void)hipMemsetAsync(ws + WS_CTR, 0,
                         (NLINES + 32) * LSTRIDE * sizeof(unsigned), stream);

    fused_decode_kernel<<<NBLK, 256, 0, stream>>>(
        h, conv_state, rec_in, conv_w, qkv_w, z_w, b_w, a_w, out_proj_w,
        dt_bias, A_log, norm_w, ws, hidden_out, new_conv, rec_out);
}